// Round 8
// baseline (131.835 us; speedup 1.0000x reference)
//
#include <hip/hip_runtime.h>
#include <hip/hip_bf16.h>
#include <math.h>
#include <stdint.h>

// Problem constants
#define NCH   8
#define DNX   128
#define DNY   128
#define KPTS  16384

typedef __attribute__((ext_vector_type(8)))  short bf16x8;   // MFMA A/B frag (8 bf16)
typedef __attribute__((ext_vector_type(16))) float f32x16;   // 32x32 MFMA C/D frag

typedef const __attribute__((address_space(1))) unsigned int* gp_t;
typedef __attribute__((address_space(3))) unsigned int* lp_t;

// pack two fp32 -> one uint32 of two bf16 (RNE) via v_cvt_pk_bf16_f32
__device__ __forceinline__ uint32_t pkbf(float lo, float hi) {
    union { __hip_bfloat162 h; uint32_t u; } v;
    v.h = __float22bfloat162_rn(make_float2(lo, hi));
    return v.u;
}

// ---------------------------------------------------------------------------
// Prep (UNCHANGED): img (fp32 planar re/im) -> B_pre (bf16, per-channel 64KB
// image in the LDS layout). Logical B[x][col], col = 2y+s (s=0:re, 1:im).
// Address: (256*col + 64*t4 + 16*q) ^ (16*(col&7)), x = 32*t4 + 8*q + j.
// ---------------------------------------------------------------------------
__global__ __launch_bounds__(256) void prep_kernel(
    const float* __restrict__ img_real,
    const float* __restrict__ img_imag,
    unsigned short* __restrict__ B_pre)
{
    int tid = blockIdx.x * 256 + threadIdx.x;   // 32768 threads total
    int y  = tid & 127;
    int xc = (tid >> 7) & 15;                   // which 8-x chunk
    int s  = (tid >> 11) & 1;
    int c  = tid >> 12;
    int t4 = xc >> 2, q = xc & 3;
    int x0 = 32 * t4 + 8 * q;
    const float* src = (s ? img_imag : img_real) + c * (DNX * DNY) + y;
    float f[8];
    #pragma unroll
    for (int j = 0; j < 8; ++j) f[j] = src[(x0 + j) * DNY];
    int col  = 2 * y + s;
    int dest = (256 * col + 64 * t4 + 16 * q) ^ (16 * (col & 7));
    uint4 val;
    val.x = pkbf(f[0], f[1]);
    val.y = pkbf(f[2], f[3]);
    val.z = pkbf(f[4], f[5]);
    val.w = pkbf(f[6], f[7]);
    *(uint4*)((char*)B_pre + (size_t)c * 65536 + dest) = val;
}

// ---------------------------------------------------------------------------
// Main: IDENTICAL to round 7 (verified correct). 32x32x16 MFMA, transposed
// operand roles: A = img tile (32 ycols x 16 x) from LDS, B = per-k phase
// (regs), D[ycol][k]. Lane-local stage-2, shfl_xor(32) epilogue.
//
// ROUND-8 IS A MEASUREMENT ROUND: kernel_launch launches this kernel 3x
// (idempotent: pure function of trj/B_pre -> out, no accumulation). The
// dur_us delta vs round 7 = 2x the warm marginal cost of the main kernel,
// resolving whether the work-invariant ~40us is the kernel or the harness
// environment (e.g. DVFS ramp after the memory-only fill).
// ---------------------------------------------------------------------------
__global__ __launch_bounds__(512, 2) void nudft_mfma_kernel(
    const float* __restrict__ trj,
    const unsigned short* __restrict__ B_pre,
    float* __restrict__ out)
{
    __shared__ __align__(16) unsigned short Bl[32768];   // 64 KB: whole channel

    const int t    = threadIdx.x;     // 0..511
    const int w    = t >> 6;          // wave 0..7
    const int lane = t & 63;
    const int l31  = lane & 31;       // this lane's k within the wave; C col
    const int hi   = lane >> 5;       // K-split half (A/B) / row +4 (C)
    const int kb   = blockIdx.x;      // 0..63
    const int c    = blockIdx.y;      // 0..7 (channel)
    const int k0w  = kb * 256 + w * 32;
    const int k    = k0w + l31;       // this lane's k-point

    // ---- trj load: one (tx,ty) per lane, coalesced
    const float trjx = trj[2 * k + 0];
    const float ty   = trj[2 * k + 1];

    // ---- stage the whole 64KB channel image: 8 x 16B per thread
    {
        const char* g = (const char*)B_pre + ((size_t)c << 16) + (t << 4);
        char* l = (char*)&Bl[0] + (t << 4);
        #pragma unroll
        for (int i = 0; i < 8; ++i)
            __builtin_amdgcn_global_load_lds(
                (gp_t)(const void*)(g + (i << 13)),
                (lp_t)(void*)(l + (i << 13)), 16, 0, 0);
    }
    __builtin_amdgcn_sched_barrier(0);   // keep DMA issue ahead of trig setup

    // ---- shared rotation constants
    const float d1 = -trjx * (1.0f / 64.0f);       // pi-units per +1 x
    float s1, c1;   sincospif(d1, &s1, &c1);
    float s16, c16; sincospif(16.0f * d1, &s16, &c16);
    float rdi, rdr; sincospif(-ty * 0.25f, &rdi, &rdr);   // y += 16 rotor

    // ---- per-lane LDS A-frag bases. addr(ct,xk) for ycol = 32ct + l31,
    // x-chunk (2xk+hi):  256*ycol + 16*((2xk+hi) ^ (ycol&7))
    //   = [256*l31 + 16*(hi^(s7&1)) + 32*((xk&3)^u)] + 8192*ct + 128*(xk>>2)
    // with s7 = lane&7 (== ycol&7), u = s7>>1.
    const int s7 = lane & 7;
    const int u  = s7 >> 1;
    const int v  = hi ^ (s7 & 1);
    const char* baseA = (const char*)&Bl[0] + 256 * l31 + 16 * v;
    const char* B0 = baseA + 32 * (0 ^ u);
    const char* B1 = baseA + 32 * (1 ^ u);
    const char* B2 = baseA + 32 * (2 ^ u);
    const char* B3 = baseA + 32 * (3 ^ u);

    float ore = 0.f, oim = 0.f;      // ksp(c,k) accumulator (lane-local)
    const f32x16 ZER16 = {0.f,0.f,0.f,0.f,0.f,0.f,0.f,0.f,
                          0.f,0.f,0.f,0.f,0.f,0.f,0.f,0.f};

    __syncthreads();   // DMA drained; the ONLY barrier in the kernel

    #pragma unroll
    for (int P = 0; P < 2; ++P) {            // x-halves: x in [64P, 64P+64)
        // ---- phase B-frags for this x-half: lane's x = 64P + 16*xk + 8*hi + j
        // Px = cis(pi * d1 * (x-64)) stored as (pxr = cos ax, pxi = -sin ax)
        bf16x8 pxr[4], pxi[4];
        {
            float ps, pc;
            sincospif(d1 * (float)(64 * P + 8 * hi - 64), &ps, &pc);
            #pragma unroll
            for (int xk = 0; xk < 4; ++xk) {
                float qc = pc, qs = ps;
                float fc[8], fs[8];
                #pragma unroll
                for (int j = 0; j < 8; ++j) {
                    fc[j] = qc; fs[j] = qs;
                    if (j < 7) {
                        float tq = qc * c1 - qs * s1;
                        qs = fmaf(qc, s1, qs * c1);
                        qc = tq;
                    }
                }
                uint32_t* pr = (uint32_t*)&pxr[xk];
                uint32_t* pi = (uint32_t*)&pxi[xk];
                #pragma unroll
                for (int p = 0; p < 4; ++p) {
                    pr[p] = pkbf(fc[2 * p], fc[2 * p + 1]);
                    pi[p] = pkbf(fs[2 * p], fs[2 * p + 1]);
                }
                if (xk < 3) {
                    float tp = pc * c16 - ps * s16;
                    ps = fmaf(pc, s16, ps * c16);
                    pc = tp;
                }
            }
        }

        // ---- stage-2 rotors (re-init per pass): p = 2q+j <-> y_local =
        // 4q + 2hi + j; (cb,sb) = cis(-pi * ty * (y-64)/64) = Py
        float cb[8], sb[8];
        {
            float bs, bc; sincospif(-ty * (float)(2 * hi - 64) * (1.0f / 64.0f), &bs, &bc);
            float qs4, qc4; sincospif(-ty * 0.0625f,   &qs4, &qc4);  // y += 4
            float os1, oc1; sincospif(-ty * 0.015625f, &os1, &oc1);  // y += 1
            float rc = bc, rs = bs;
            #pragma unroll
            for (int q = 0; q < 4; ++q) {
                cb[2 * q] = rc;  sb[2 * q] = rs;
                cb[2 * q + 1] = rc * oc1 - rs * os1;
                sb[2 * q + 1] = fmaf(rc, os1, rs * oc1);
                if (q < 3) {
                    float tz = rc * qc4 - rs * qs4;
                    rs = fmaf(rc, qs4, rs * qc4);
                    rc = tz;
                }
            }
        }

        // ---- ct loop: 8 blocks of 32 ycols (16 y) each
        #pragma unroll 1
        for (int ct = 0; ct < 8; ++ct) {
            const int off = 8192 * ct + 128 * P;
            bf16x8 f0 = *(const bf16x8*)(B0 + off);
            bf16x8 f1 = *(const bf16x8*)(B1 + off);
            bf16x8 f2 = *(const bf16x8*)(B2 + off);
            bf16x8 f3 = *(const bf16x8*)(B3 + off);
            f32x16 a1, a2;
            __builtin_amdgcn_s_setprio(1);
            a1 = __builtin_amdgcn_mfma_f32_32x32x16_bf16(f0, pxr[0], ZER16, 0,0,0);
            a2 = __builtin_amdgcn_mfma_f32_32x32x16_bf16(f0, pxi[0], ZER16, 0,0,0);
            a1 = __builtin_amdgcn_mfma_f32_32x32x16_bf16(f1, pxr[1], a1,    0,0,0);
            a2 = __builtin_amdgcn_mfma_f32_32x32x16_bf16(f1, pxi[1], a2,    0,0,0);
            a1 = __builtin_amdgcn_mfma_f32_32x32x16_bf16(f2, pxr[2], a1,    0,0,0);
            a2 = __builtin_amdgcn_mfma_f32_32x32x16_bf16(f2, pxi[2], a2,    0,0,0);
            a1 = __builtin_amdgcn_mfma_f32_32x32x16_bf16(f3, pxr[3], a1,    0,0,0);
            a2 = __builtin_amdgcn_mfma_f32_32x32x16_bf16(f3, pxi[3], a2,    0,0,0);
            __builtin_amdgcn_s_setprio(0);
            // stage 2: rows 4q+2j (re) / 4q+2j+1 (im) -> S(k,y); out += S*Py
            #pragma unroll
            for (int q = 0; q < 4; ++q) {
                #pragma unroll
                for (int j = 0; j < 2; ++j) {
                    const int e = 4 * q + 2 * j;
                    const int p = 2 * q + j;
                    float Sre = a1[e]     - a2[e + 1];
                    float Sim = a1[e + 1] + a2[e];
                    ore = fmaf(Sre,  cb[p], ore);
                    ore = fmaf(-Sim, sb[p], ore);
                    oim = fmaf(Sre,  sb[p], oim);
                    oim = fmaf(Sim,  cb[p], oim);
                }
            }
            // advance all 8 rotors by y += 16
            #pragma unroll
            for (int p = 0; p < 8; ++p) {
                float tz = cb[p] * rdr - sb[p] * rdi;
                sb[p] = fmaf(cb[p], rdi, sb[p] * rdr);
                cb[p] = tz;
            }
        }
    }

    // ---- epilogue: combine the two x/k-split halves held by lanes l and l+32
    float rre = ore + __shfl_xor(ore, 32);
    float rim = oim + __shfl_xor(oim, 32);
    if (lane < 32) {
        out[(size_t)c * KPTS + k]                      = rre;
        out[(size_t)NCH * KPTS + (size_t)c * KPTS + k] = rim;
    }
}

extern "C" void kernel_launch(void* const* d_in, const int* in_sizes, int n_in,
                              void* d_out, int out_size, void* d_ws, size_t ws_size,
                              hipStream_t stream)
{
    const float* img_real = (const float*)d_in[0];  // (8,128,128) fp32
    const float* img_imag = (const float*)d_in[1];  // (8,128,128) fp32
    const float* trj      = (const float*)d_in[2];  // (16384,2) fp32
    float* out = (float*)d_out;                      // planar: re block then im block
    unsigned short* B_pre = (unsigned short*)d_ws;   // 512 KB bf16 pre-swizzled img

    prep_kernel<<<128, 256, 0, stream>>>(img_real, img_imag, B_pre);
    // MEASUREMENT: 3x idempotent launches. dur_us delta vs round 7 = 2x the
    // warm marginal cost of the main kernel (separates kernel cost from any
    // first-run/environmental premium).
    nudft_mfma_kernel<<<dim3(64, 8), 512, 0, stream>>>(trj, B_pre, out);
    nudft_mfma_kernel<<<dim3(64, 8), 512, 0, stream>>>(trj, B_pre, out);
    nudft_mfma_kernel<<<dim3(64, 8), 512, 0, stream>>>(trj, B_pre, out);
}

// Round 10
// 81.858 us; speedup vs baseline: 1.6105x; 1.6105x over previous
//
#include <hip/hip_runtime.h>
#include <hip/hip_bf16.h>
#include <math.h>
#include <stdint.h>

// Problem constants
#define NCH   8
#define DNX   128
#define DNY   128
#define KPTS  16384

typedef __attribute__((ext_vector_type(8)))  short bf16x8;   // MFMA A/B frag (8 bf16)
typedef __attribute__((ext_vector_type(16))) float f32x16;   // 32x32 MFMA C/D frag

typedef const __attribute__((address_space(1))) unsigned int* gp_t;
typedef __attribute__((address_space(3))) unsigned int* lp_t;

// pack two fp32 -> one uint32 of two bf16 (RNE)
__device__ __forceinline__ uint32_t pkbf(float lo, float hi) {
    union { __hip_bfloat162 h; uint32_t u; } v;
    v.h = __float22bfloat162_rn(make_float2(lo, hi));
    return v.u;
}

// ---------------------------------------------------------------------------
// Prep 1 (UNCHANGED, verified r0-r7): img -> B_pre (bf16, per-channel 64KB,
// LDS-ready layout). Logical B[x][col], col = 2y+s. Address:
// (256*col + 64*t4 + 16*q) ^ (16*(col&7)), x = 32*t4 + 8*q + j.
// ---------------------------------------------------------------------------
__global__ __launch_bounds__(256) void prep_kernel(
    const float* __restrict__ img_real,
    const float* __restrict__ img_imag,
    unsigned short* __restrict__ B_pre)
{
    int tid = blockIdx.x * 256 + threadIdx.x;   // 32768 threads total
    int y  = tid & 127;
    int xc = (tid >> 7) & 15;
    int s  = (tid >> 11) & 1;
    int c  = tid >> 12;
    int t4 = xc >> 2, q = xc & 3;
    int x0 = 32 * t4 + 8 * q;
    const float* src = (s ? img_imag : img_real) + c * (DNX * DNY) + y;
    float f[8];
    #pragma unroll
    for (int j = 0; j < 8; ++j) f[j] = src[(x0 + j) * DNY];
    int col  = 2 * y + s;
    int dest = (256 * col + 64 * t4 + 16 * q) ^ (16 * (col & 7));
    uint4 val;
    val.x = pkbf(f[0], f[1]);
    val.y = pkbf(f[2], f[3]);
    val.z = pkbf(f[4], f[5]);
    val.w = pkbf(f[6], f[7]);
    *(uint4*)((char*)B_pre + (size_t)c * 65536 + dest) = val;
}

// ---------------------------------------------------------------------------
// Prep 2 (as r9): phase_x table in MFMA-B-fragment layout.
// PT_re[(kg*8 + xk8)*1024 + lane*16] = bf16x8 of cospi(d1*(x-64)),
// x = 16*xk8 + 8*hi + j, lane = hi*32 + l31, k = kg*32 + l31, d1 = -tx/64.
// PT_im at +4MB. Total 8MB at ws+1MB (ws is 256MB per the poison fill).
// ---------------------------------------------------------------------------
__global__ __launch_bounds__(256) void prep_phase_kernel(
    const float* __restrict__ trj,
    unsigned short* __restrict__ PT)
{
    int tid = blockIdx.x * 256 + threadIdx.x;   // 0..131071
    int l31 = tid & 31;
    int xk8 = (tid >> 5) & 7;
    int kg  = tid >> 8;
    int k   = kg * 32 + l31;
    float tx = trj[2 * k];
    float d1 = -tx * (1.0f / 64.0f);
    float s1, c1; sincospif(d1, &s1, &c1);
    #pragma unroll
    for (int hi = 0; hi < 2; ++hi) {
        float qs, qc;
        sincospif(d1 * (float)(16 * xk8 + 8 * hi - 64), &qs, &qc);
        float fc[8], fs[8];
        #pragma unroll
        for (int j = 0; j < 8; ++j) {
            fc[j] = qc; fs[j] = qs;
            if (j < 7) {
                float tq = qc * c1 - qs * s1;
                qs = fmaf(qc, s1, qs * c1);
                qc = tq;
            }
        }
        uint4 re, im;
        re.x = pkbf(fc[0], fc[1]); re.y = pkbf(fc[2], fc[3]);
        re.z = pkbf(fc[4], fc[5]); re.w = pkbf(fc[6], fc[7]);
        im.x = pkbf(fs[0], fs[1]); im.y = pkbf(fs[2], fs[3]);
        im.z = pkbf(fs[4], fs[5]); im.w = pkbf(fs[6], fs[7]);
        size_t off = (size_t)(kg * 8 + xk8) * 1024 + (size_t)(hi * 32 + l31) * 16;
        *(uint4*)((char*)PT + off)              = re;
        *(uint4*)((char*)PT + (4u << 20) + off) = im;
    }
}

// ---------------------------------------------------------------------------
// Main, round-10: ISOLATION ROUND. r9 failed (absmax 48.5, ~10% systematic
// error) with three changes vs the verified r7; the only unverified one was
// the v_pk_fma_f32 neg_lo/neg_hi inline asm. This round KEEPS (a) the phase
// table (address algebra re-verified identical to r7's per-pass form) and
// (b) the merged K=128 MFMA chain (exact f32 reordering), and REVERTS the
// stage-2 to r7's scalar fmaf form (verified passing twice).
// VALU/wave ~1750 -> ~750 (trig gen removed, stage-2 halved).
// ---------------------------------------------------------------------------
__global__ __launch_bounds__(512, 1) void nudft_mfma_kernel(
    const float* __restrict__ trj,
    const unsigned short* __restrict__ B_pre,
    const unsigned short* __restrict__ PT,
    float* __restrict__ out)
{
    __shared__ __align__(16) unsigned short Bl[32768];   // 64 KB: whole channel

    const int t    = threadIdx.x;     // 0..511
    const int w    = t >> 6;          // wave 0..7
    const int lane = t & 63;
    const int l31  = lane & 31;       // this lane's k within the wave; C col
    const int hi   = lane >> 5;       // K-split half (A/B) / row +4 (C)
    const int kb   = blockIdx.x;      // 0..63
    const int c    = blockIdx.y;      // 0..7 (channel)
    const int k0w  = kb * 256 + w * 32;
    const int k    = k0w + l31;       // this lane's k-point

    // ---- stage the whole 64KB channel image: 8 x 16B per thread
    {
        const char* g = (const char*)B_pre + ((size_t)c << 16) + (t << 4);
        char* l = (char*)&Bl[0] + (t << 4);
        #pragma unroll
        for (int i = 0; i < 8; ++i)
            __builtin_amdgcn_global_load_lds(
                (gp_t)(const void*)(g + (i << 13)),
                (lp_t)(void*)(l + (i << 13)), 16, 0, 0);
    }
    __builtin_amdgcn_sched_barrier(0);

    // ---- load phase fragments (kg = kb*8 + w)
    bf16x8 pxr[8], pxi[8];
    {
        const char* ptre = (const char*)PT + (size_t)(kb * 8 + w) * 8192 + (lane << 4);
        const char* ptim = ptre + (4u << 20);
        #pragma unroll
        for (int i = 0; i < 8; ++i) {
            pxr[i] = *(const bf16x8*)(ptre + i * 1024);
            pxi[i] = *(const bf16x8*)(ptim + i * 1024);
        }
    }

    // ---- trj: only ty needed
    const float ty = trj[2 * k + 1];

    // ---- stage-2 rotors (r7's verified scalar form). p = 2q+j <-> y_local
    // = 4q + 2hi + j; (cb,sb) = cis(-pi*ty*(y-64)/64); ct-step = cis(-pi ty/4)
    float rdi, rdr; sincospif(-ty * 0.25f, &rdi, &rdr);
    float cb[8], sb[8];
    {
        float bs, bc; sincospif(-ty * (float)(2 * hi - 64) * (1.0f / 64.0f), &bs, &bc);
        float qs4, qc4; sincospif(-ty * 0.0625f,   &qs4, &qc4);  // y += 4
        float os1, oc1; sincospif(-ty * 0.015625f, &os1, &oc1);  // y += 1
        float rc = bc, rs = bs;
        #pragma unroll
        for (int q = 0; q < 4; ++q) {
            cb[2 * q] = rc;  sb[2 * q] = rs;
            cb[2 * q + 1] = rc * oc1 - rs * os1;
            sb[2 * q + 1] = fmaf(rc, os1, rs * oc1);
            if (q < 3) {
                float tz = rc * qc4 - rs * qs4;
                rs = fmaf(rc, qs4, rs * qc4);
                rc = tz;
            }
        }
    }
    float ore = 0.f, oim = 0.f;

    // ---- per-lane LDS A-frag bases (identical to r7/r9 derivation)
    const int s7 = lane & 7;
    const int u  = s7 >> 1;
    const int v  = hi ^ (s7 & 1);
    const char* baseA = (const char*)&Bl[0] + 256 * l31 + 16 * v;
    const char* B0 = baseA + 32 * (0 ^ u);
    const char* B1 = baseA + 32 * (1 ^ u);
    const char* B2 = baseA + 32 * (2 ^ u);
    const char* B3 = baseA + 32 * (3 ^ u);
    const f32x16 ZER16 = {0.f,0.f,0.f,0.f,0.f,0.f,0.f,0.f,
                          0.f,0.f,0.f,0.f,0.f,0.f,0.f,0.f};

    __syncthreads();   // DMA drained; the ONLY barrier in the kernel

    #pragma unroll 1
    for (int ct = 0; ct < 8; ++ct) {
        const int off = 8192 * ct;
        bf16x8 f0 = *(const bf16x8*)(B0 + off);
        bf16x8 f1 = *(const bf16x8*)(B1 + off);
        bf16x8 f2 = *(const bf16x8*)(B2 + off);
        bf16x8 f3 = *(const bf16x8*)(B3 + off);
        bf16x8 f4 = *(const bf16x8*)(B0 + off + 128);
        bf16x8 f5 = *(const bf16x8*)(B1 + off + 128);
        bf16x8 f6 = *(const bf16x8*)(B2 + off + 128);
        bf16x8 f7 = *(const bf16x8*)(B3 + off + 128);
        f32x16 a1, a2;
        __builtin_amdgcn_s_setprio(1);
        a1 = __builtin_amdgcn_mfma_f32_32x32x16_bf16(f0, pxr[0], ZER16, 0,0,0);
        a2 = __builtin_amdgcn_mfma_f32_32x32x16_bf16(f0, pxi[0], ZER16, 0,0,0);
        a1 = __builtin_amdgcn_mfma_f32_32x32x16_bf16(f1, pxr[1], a1,    0,0,0);
        a2 = __builtin_amdgcn_mfma_f32_32x32x16_bf16(f1, pxi[1], a2,    0,0,0);
        a1 = __builtin_amdgcn_mfma_f32_32x32x16_bf16(f2, pxr[2], a1,    0,0,0);
        a2 = __builtin_amdgcn_mfma_f32_32x32x16_bf16(f2, pxi[2], a2,    0,0,0);
        a1 = __builtin_amdgcn_mfma_f32_32x32x16_bf16(f3, pxr[3], a1,    0,0,0);
        a2 = __builtin_amdgcn_mfma_f32_32x32x16_bf16(f3, pxi[3], a2,    0,0,0);
        a1 = __builtin_amdgcn_mfma_f32_32x32x16_bf16(f4, pxr[4], a1,    0,0,0);
        a2 = __builtin_amdgcn_mfma_f32_32x32x16_bf16(f4, pxi[4], a2,    0,0,0);
        a1 = __builtin_amdgcn_mfma_f32_32x32x16_bf16(f5, pxr[5], a1,    0,0,0);
        a2 = __builtin_amdgcn_mfma_f32_32x32x16_bf16(f5, pxi[5], a2,    0,0,0);
        a1 = __builtin_amdgcn_mfma_f32_32x32x16_bf16(f6, pxr[6], a1,    0,0,0);
        a2 = __builtin_amdgcn_mfma_f32_32x32x16_bf16(f6, pxi[6], a2,    0,0,0);
        a1 = __builtin_amdgcn_mfma_f32_32x32x16_bf16(f7, pxr[7], a1,    0,0,0);
        a2 = __builtin_amdgcn_mfma_f32_32x32x16_bf16(f7, pxi[7], a2,    0,0,0);
        __builtin_amdgcn_s_setprio(0);
        // stage 2 (once per ct) — r7's verified scalar form
        #pragma unroll
        for (int q = 0; q < 4; ++q) {
            #pragma unroll
            for (int j = 0; j < 2; ++j) {
                const int e = 4 * q + 2 * j;
                const int p = 2 * q + j;
                float Sre = a1[e]     - a2[e + 1];
                float Sim = a1[e + 1] + a2[e];
                ore = fmaf(Sre,  cb[p], ore);
                ore = fmaf(-Sim, sb[p], ore);
                oim = fmaf(Sre,  sb[p], oim);
                oim = fmaf(Sim,  cb[p], oim);
            }
        }
        // advance all 8 rotors by y += 16
        #pragma unroll
        for (int p = 0; p < 8; ++p) {
            float tz = cb[p] * rdr - sb[p] * rdi;
            sb[p] = fmaf(cb[p], rdi, sb[p] * rdr);
            cb[p] = tz;
        }
    }

    // ---- epilogue: combine the x/k-split halves held by lanes l and l+32
    float rre = ore + __shfl_xor(ore, 32);
    float rim = oim + __shfl_xor(oim, 32);
    if (lane < 32) {
        out[(size_t)c * KPTS + k]                      = rre;
        out[(size_t)NCH * KPTS + (size_t)c * KPTS + k] = rim;
    }
}

extern "C" void kernel_launch(void* const* d_in, const int* in_sizes, int n_in,
                              void* d_out, int out_size, void* d_ws, size_t ws_size,
                              hipStream_t stream)
{
    const float* img_real = (const float*)d_in[0];  // (8,128,128) fp32
    const float* img_imag = (const float*)d_in[1];  // (8,128,128) fp32
    const float* trj      = (const float*)d_in[2];  // (16384,2) fp32
    float* out = (float*)d_out;                      // planar: re block then im block
    unsigned short* B_pre = (unsigned short*)d_ws;               // 512 KB
    unsigned short* PT    = (unsigned short*)((char*)d_ws + (1u << 20));  // 8 MB

    prep_kernel<<<128, 256, 0, stream>>>(img_real, img_imag, B_pre);
    prep_phase_kernel<<<512, 256, 0, stream>>>(trj, PT);
    nudft_mfma_kernel<<<dim3(64, 8), 512, 0, stream>>>(trj, B_pre, PT, out);
}

// Round 11
// 75.370 us; speedup vs baseline: 1.7492x; 1.0861x over previous
//
#include <hip/hip_runtime.h>
#include <hip/hip_bf16.h>
#include <math.h>
#include <stdint.h>

// Problem constants
#define NCH   8
#define DNX   128
#define DNY   128
#define KPTS  16384

typedef __attribute__((ext_vector_type(8)))  short bf16x8;   // MFMA A/B frag (8 bf16)
typedef __attribute__((ext_vector_type(16))) float f32x16;   // 32x32 MFMA C/D frag

typedef const __attribute__((address_space(1))) unsigned int* gp_t;
typedef __attribute__((address_space(3))) unsigned int* lp_t;

// pack two fp32 -> one uint32 of two bf16 (RNE)
__device__ __forceinline__ uint32_t pkbf(float lo, float hi) {
    union { __hip_bfloat162 h; uint32_t u; } v;
    v.h = __float22bfloat162_rn(make_float2(lo, hi));
    return v.u;
}

// ---------------------------------------------------------------------------
// Prep 1 (FOLDED): img -> B_pre with center-symmetric x-fold.
// For u' = 0..63:  f_plus(u',y)  = f(64+u',y) + f(63-u',y)   -> x-slot u'
//                  f_minus(u',y) = f(64+u',y) - f(63-u',y)   -> x-slot 64+u'
// Same 64KB/channel layout as all prior rounds:
// dest(x_slot,col) = (256*col + 64*t4 + 16*q) ^ (16*(col&7)), col = 2y+s.
// ---------------------------------------------------------------------------
__global__ __launch_bounds__(256) void prep_kernel(
    const float* __restrict__ img_real,
    const float* __restrict__ img_imag,
    unsigned short* __restrict__ B_pre)
{
    int tid = blockIdx.x * 256 + threadIdx.x;   // 16384 threads total
    int y  = tid & 127;
    int uc = (tid >> 7) & 7;                    // u-chunk 0..7, u0 = 8*uc
    int s  = (tid >> 10) & 1;
    int c  = tid >> 11;
    int u0 = 8 * uc;
    const float* src = (s ? img_imag : img_real) + c * (DNX * DNY) + y;
    float fp[8], fm[8];
    #pragma unroll
    for (int j = 0; j < 8; ++j) {
        float a = src[(64 + u0 + j) * DNY];
        float b = src[(63 - u0 - j) * DNY];
        fp[j] = a + b;
        fm[j] = a - b;
    }
    int col = 2 * y + s;
    int xo  = 16 * (col & 7);
    int t4p = uc >> 2, q = uc & 3;
    int destp = (256 * col + 64 * t4p       + 16 * q) ^ xo;   // slot u0
    int destm = (256 * col + 64 * (t4p + 2) + 16 * q) ^ xo;   // slot 64+u0
    uint4 vp, vm;
    vp.x = pkbf(fp[0], fp[1]); vp.y = pkbf(fp[2], fp[3]);
    vp.z = pkbf(fp[4], fp[5]); vp.w = pkbf(fp[6], fp[7]);
    vm.x = pkbf(fm[0], fm[1]); vm.y = pkbf(fm[2], fm[3]);
    vm.z = pkbf(fm[4], fm[5]); vm.w = pkbf(fm[6], fm[7]);
    char* base = (char*)B_pre + (size_t)c * 65536;
    *(uint4*)(base + destp) = vp;
    *(uint4*)(base + destm) = vm;
}

// ---------------------------------------------------------------------------
// Prep 2 (FOLDED phases): PT[(kg*8 + slot)*1024 + lane*16], kg = k>>5.
// slots 0..3: cos frags, slots 4..7: sin frags. Fragment element (hi,j) of
// slot m: angle = pi * d1 * (16m + 8hi + j + 0.5), d1 = -tx/64. 4 MB total.
// ---------------------------------------------------------------------------
__global__ __launch_bounds__(256) void prep_phase_kernel(
    const float* __restrict__ trj,
    unsigned short* __restrict__ PT)
{
    int tid = blockIdx.x * 256 + threadIdx.x;   // 0..65535
    int l31 = tid & 31;
    int m   = (tid >> 5) & 3;
    int kg  = tid >> 7;                         // 0..511
    int k   = kg * 32 + l31;
    float tx = trj[2 * k];
    float d1 = -tx * (1.0f / 64.0f);
    float s1, c1; sincospif(d1, &s1, &c1);
    #pragma unroll
    for (int hi = 0; hi < 2; ++hi) {
        float qs, qc;
        sincospif(d1 * ((float)(16 * m + 8 * hi) + 0.5f), &qs, &qc);
        float fc[8], fs[8];
        #pragma unroll
        for (int j = 0; j < 8; ++j) {
            fc[j] = qc; fs[j] = qs;
            if (j < 7) {
                float tq = qc * c1 - qs * s1;
                qs = fmaf(qc, s1, qs * c1);
                qc = tq;
            }
        }
        uint4 re, im;
        re.x = pkbf(fc[0], fc[1]); re.y = pkbf(fc[2], fc[3]);
        re.z = pkbf(fc[4], fc[5]); re.w = pkbf(fc[6], fc[7]);
        im.x = pkbf(fs[0], fs[1]); im.y = pkbf(fs[2], fs[3]);
        im.z = pkbf(fs[4], fs[5]); im.w = pkbf(fs[6], fs[7]);
        size_t lo = (size_t)(hi * 32 + l31) * 16;
        *(uint4*)((char*)PT + (size_t)(kg * 8 + m)     * 1024 + lo) = re;
        *(uint4*)((char*)PT + (size_t)(kg * 8 + m + 4) * 1024 + lo) = im;
    }
}

// ---------------------------------------------------------------------------
// Main, round-11: HALVE MFMA FLOPs (the one quantity invariant across all
// prior rounds; r8's warm-marginal 25us == 16384 MFMA-cyc/SIMD at the
// ~655MHz post-fill clock, exactly).
// Center-symmetric x-fold: exp(-i t (x-64)) = cis(pi tx/128) * cis(-t(x-63.5));
// 64 exact pairs -> stage-1 = cos-matmul over f_plus + i * sin-matmul over
// f_minus, contraction 64. Combine signs IDENTICAL to verified r10
// (Sre = a1[e]-a2[e+1], Sim = a1[e+1]+a2[e]); one final per-k rotation
// cis(pi tx/128) in the epilogue.
// Each wave owns 64 k (2 k-sets sharing every ds_read):
//   per SIMD (2 waves): MFMA 8192 cyc (was 16384), LDS 6144, VALU ~6400.
// Grid (32,8) = 256 blocks, 8 waves, (512,1): ~210 live VGPR < 256, no spill.
// ---------------------------------------------------------------------------
__global__ __launch_bounds__(512, 1) void nudft_mfma_kernel(
    const float* __restrict__ trj,
    const unsigned short* __restrict__ B_pre,
    const unsigned short* __restrict__ PT,
    float* __restrict__ out)
{
    __shared__ __align__(16) unsigned short Bl[32768];   // 64 KB folded channel

    const int t    = threadIdx.x;     // 0..511
    const int w    = t >> 6;          // wave 0..7
    const int lane = t & 63;
    const int l31  = lane & 31;
    const int hi   = lane >> 5;
    const int kb   = blockIdx.x;      // 0..31
    const int c    = blockIdx.y;      // 0..7
    const int k0w  = kb * 512 + w * 64;
    const int kA   = k0w + l31;        // k-set 0
    const int kB   = k0w + 32 + l31;   // k-set 1

    // ---- stage the whole 64KB folded channel image
    {
        const char* g = (const char*)B_pre + ((size_t)c << 16) + (t << 4);
        char* l = (char*)&Bl[0] + (t << 4);
        #pragma unroll
        for (int i = 0; i < 8; ++i)
            __builtin_amdgcn_global_load_lds(
                (gp_t)(const void*)(g + (i << 13)),
                (lp_t)(void*)(l + (i << 13)), 16, 0, 0);
    }
    __builtin_amdgcn_sched_barrier(0);

    // ---- load phase fragments: kg(ks) = kb*16 + 2w + ks
    bf16x8 pc0[4], ps0[4], pc1[4], ps1[4];
    {
        const char* base = (const char*)PT
                         + (size_t)(kb * 16 + 2 * w) * 8192 + (lane << 4);
        #pragma unroll
        for (int m = 0; m < 4; ++m) {
            pc0[m] = *(const bf16x8*)(base + (m    ) * 1024);
            ps0[m] = *(const bf16x8*)(base + (m + 4) * 1024);
            pc1[m] = *(const bf16x8*)(base + 8192 + (m    ) * 1024);
            ps1[m] = *(const bf16x8*)(base + 8192 + (m + 4) * 1024);
        }
    }

    // ---- trj: ty per k-set (rotors), tx per k-set (final rotation)
    const float tyA = trj[2 * kA + 1];
    const float tyB = trj[2 * kB + 1];
    float srA, crA; sincospif(trj[2 * kA] * 0.0078125f, &srA, &crA);
    float srB, crB; sincospif(trj[2 * kB] * 0.0078125f, &srB, &crB);

    // ---- stage-2 rotors per k-set (r10's verified form)
    float rdiA, rdrA; sincospif(-tyA * 0.25f, &rdiA, &rdrA);
    float rdiB, rdrB; sincospif(-tyB * 0.25f, &rdiB, &rdrB);
    float cbA[8], sbA[8], cbB[8], sbB[8];
    #pragma unroll
    for (int ks = 0; ks < 2; ++ks) {
        const float ty = ks ? tyB : tyA;
        float* cb = ks ? cbB : cbA;
        float* sb = ks ? sbB : sbA;
        float bs, bc; sincospif(-ty * (float)(2 * hi - 64) * (1.0f / 64.0f), &bs, &bc);
        float qs4, qc4; sincospif(-ty * 0.0625f,   &qs4, &qc4);
        float os1, oc1; sincospif(-ty * 0.015625f, &os1, &oc1);
        float rc = bc, rs = bs;
        #pragma unroll
        for (int q = 0; q < 4; ++q) {
            cb[2 * q] = rc;  sb[2 * q] = rs;
            cb[2 * q + 1] = rc * oc1 - rs * os1;
            sb[2 * q + 1] = fmaf(rc, os1, rs * oc1);
            if (q < 3) {
                float tz = rc * qc4 - rs * qs4;
                rs = fmaf(rc, qs4, rs * qc4);
                rc = tz;
            }
        }
    }
    float oreA = 0.f, oimA = 0.f, oreB = 0.f, oimB = 0.f;

    // ---- per-lane LDS bases (identical derivation to r7/r10)
    const int s7 = lane & 7;
    const int u  = s7 >> 1;
    const int v  = hi ^ (s7 & 1);
    const char* baseA = (const char*)&Bl[0] + 256 * l31 + 16 * v;
    const char* B0 = baseA + 32 * (0 ^ u);
    const char* B1 = baseA + 32 * (1 ^ u);
    const char* B2 = baseA + 32 * (2 ^ u);
    const char* B3 = baseA + 32 * (3 ^ u);
    const f32x16 ZER16 = {0.f,0.f,0.f,0.f,0.f,0.f,0.f,0.f,
                          0.f,0.f,0.f,0.f,0.f,0.f,0.f,0.f};

    __syncthreads();   // DMA drained; the ONLY barrier

    #pragma unroll 1
    for (int ct = 0; ct < 8; ++ct) {
        const int off = 8192 * ct;
        bf16x8 f0 = *(const bf16x8*)(B0 + off);          // plus-plane chunks
        bf16x8 f1 = *(const bf16x8*)(B1 + off);
        bf16x8 f2 = *(const bf16x8*)(B2 + off);
        bf16x8 f3 = *(const bf16x8*)(B3 + off);
        bf16x8 f4 = *(const bf16x8*)(B0 + off + 128);    // minus-plane chunks
        bf16x8 f5 = *(const bf16x8*)(B1 + off + 128);
        bf16x8 f6 = *(const bf16x8*)(B2 + off + 128);
        bf16x8 f7 = *(const bf16x8*)(B3 + off + 128);
        f32x16 a1, a2, b1, b2;
        __builtin_amdgcn_s_setprio(1);
        // 4 independent chains (dep distance 4): a=kset0, b=kset1
        a1 = __builtin_amdgcn_mfma_f32_32x32x16_bf16(f0, pc0[0], ZER16, 0,0,0);
        a2 = __builtin_amdgcn_mfma_f32_32x32x16_bf16(f4, ps0[0], ZER16, 0,0,0);
        b1 = __builtin_amdgcn_mfma_f32_32x32x16_bf16(f0, pc1[0], ZER16, 0,0,0);
        b2 = __builtin_amdgcn_mfma_f32_32x32x16_bf16(f4, ps1[0], ZER16, 0,0,0);
        a1 = __builtin_amdgcn_mfma_f32_32x32x16_bf16(f1, pc0[1], a1,    0,0,0);
        a2 = __builtin_amdgcn_mfma_f32_32x32x16_bf16(f5, ps0[1], a2,    0,0,0);
        b1 = __builtin_amdgcn_mfma_f32_32x32x16_bf16(f1, pc1[1], b1,    0,0,0);
        b2 = __builtin_amdgcn_mfma_f32_32x32x16_bf16(f5, ps1[1], b2,    0,0,0);
        a1 = __builtin_amdgcn_mfma_f32_32x32x16_bf16(f2, pc0[2], a1,    0,0,0);
        a2 = __builtin_amdgcn_mfma_f32_32x32x16_bf16(f6, ps0[2], a2,    0,0,0);
        b1 = __builtin_amdgcn_mfma_f32_32x32x16_bf16(f2, pc1[2], b1,    0,0,0);
        b2 = __builtin_amdgcn_mfma_f32_32x32x16_bf16(f6, ps1[2], b2,    0,0,0);
        a1 = __builtin_amdgcn_mfma_f32_32x32x16_bf16(f3, pc0[3], a1,    0,0,0);
        a2 = __builtin_amdgcn_mfma_f32_32x32x16_bf16(f7, ps0[3], a2,    0,0,0);
        b1 = __builtin_amdgcn_mfma_f32_32x32x16_bf16(f3, pc1[3], b1,    0,0,0);
        b2 = __builtin_amdgcn_mfma_f32_32x32x16_bf16(f7, ps1[3], b2,    0,0,0);
        __builtin_amdgcn_s_setprio(0);
        // stage 2 per k-set (combine signs verified in r7/r10)
        #pragma unroll
        for (int q = 0; q < 4; ++q) {
            #pragma unroll
            for (int j = 0; j < 2; ++j) {
                const int e = 4 * q + 2 * j;
                const int p = 2 * q + j;
                {
                    float Sre = a1[e]     - a2[e + 1];
                    float Sim = a1[e + 1] + a2[e];
                    oreA = fmaf(Sre,  cbA[p], oreA);
                    oreA = fmaf(-Sim, sbA[p], oreA);
                    oimA = fmaf(Sre,  sbA[p], oimA);
                    oimA = fmaf(Sim,  cbA[p], oimA);
                }
                {
                    float Sre = b1[e]     - b2[e + 1];
                    float Sim = b1[e + 1] + b2[e];
                    oreB = fmaf(Sre,  cbB[p], oreB);
                    oreB = fmaf(-Sim, sbB[p], oreB);
                    oimB = fmaf(Sre,  sbB[p], oimB);
                    oimB = fmaf(Sim,  cbB[p], oimB);
                }
            }
        }
        // advance rotors (y += 16)
        #pragma unroll
        for (int p = 0; p < 8; ++p) {
            float tzA = cbA[p] * rdrA - sbA[p] * rdiA;
            sbA[p] = fmaf(cbA[p], rdiA, sbA[p] * rdrA);
            cbA[p] = tzA;
            float tzB = cbB[p] * rdrB - sbB[p] * rdiB;
            sbB[p] = fmaf(cbB[p], rdiB, sbB[p] * rdrB);
            cbB[p] = tzB;
        }
    }

    // ---- epilogue: fold lane-halves, apply final rotation cis(pi*tx/128)
    {
        float r0 = oreA + __shfl_xor(oreA, 32);
        float i0 = oimA + __shfl_xor(oimA, 32);
        float r1 = oreB + __shfl_xor(oreB, 32);
        float i1 = oimB + __shfl_xor(oimB, 32);
        if (lane < 32) {
            out[(size_t)c * KPTS + kA]                      = r0 * crA - i0 * srA;
            out[(size_t)NCH * KPTS + (size_t)c * KPTS + kA] = fmaf(r0, srA, i0 * crA);
            out[(size_t)c * KPTS + kB]                      = r1 * crB - i1 * srB;
            out[(size_t)NCH * KPTS + (size_t)c * KPTS + kB] = fmaf(r1, srB, i1 * crB);
        }
    }
}

extern "C" void kernel_launch(void* const* d_in, const int* in_sizes, int n_in,
                              void* d_out, int out_size, void* d_ws, size_t ws_size,
                              hipStream_t stream)
{
    const float* img_real = (const float*)d_in[0];  // (8,128,128) fp32
    const float* img_imag = (const float*)d_in[1];  // (8,128,128) fp32
    const float* trj      = (const float*)d_in[2];  // (16384,2) fp32
    float* out = (float*)d_out;                      // planar: re block then im block
    unsigned short* B_pre = (unsigned short*)d_ws;               // 512 KB (folded)
    unsigned short* PT    = (unsigned short*)((char*)d_ws + (1u << 20));  // 4 MB

    prep_kernel<<<64, 256, 0, stream>>>(img_real, img_imag, B_pre);
    prep_phase_kernel<<<256, 256, 0, stream>>>(trj, PT);
    nudft_mfma_kernel<<<dim3(32, 8), 512, 0, stream>>>(trj, B_pre, PT, out);
}

// Round 12
// 73.438 us; speedup vs baseline: 1.7952x; 1.0263x over previous
//
#include <hip/hip_runtime.h>
#include <hip/hip_bf16.h>
#include <math.h>
#include <stdint.h>

// Problem constants
#define NCH   8
#define DNX   128
#define DNY   128
#define KPTS  16384

typedef __attribute__((ext_vector_type(8)))  short bf16x8;   // MFMA A/B frag (8 bf16)
typedef __attribute__((ext_vector_type(16))) float f32x16;   // 32x32 MFMA C/D frag

typedef const __attribute__((address_space(1))) unsigned int* gp_t;
typedef __attribute__((address_space(3))) unsigned int* lp_t;

// pack two fp32 -> one uint32 of two bf16 (RNE)
__device__ __forceinline__ uint32_t pkbf(float lo, float hi) {
    union { __hip_bfloat162 h; uint32_t u; } v;
    v.h = __float22bfloat162_rn(make_float2(lo, hi));
    return v.u;
}

// ---------------------------------------------------------------------------
// Prep (UNCHANGED from verified r11): img -> B_pre with center-symmetric
// x-fold. u' = 0..63: f_plus(u',y) = f(64+u',y)+f(63-u',y) -> x-slot u';
// f_minus -> x-slot 64+u'. dest(x_slot,col) =
// (256*col + 64*t4 + 16*q) ^ (16*(col&7)), col = 2y+s.
// ---------------------------------------------------------------------------
__global__ __launch_bounds__(256) void prep_kernel(
    const float* __restrict__ img_real,
    const float* __restrict__ img_imag,
    unsigned short* __restrict__ B_pre)
{
    int tid = blockIdx.x * 256 + threadIdx.x;   // 16384 threads total
    int y  = tid & 127;
    int uc = (tid >> 7) & 7;                    // u-chunk 0..7, u0 = 8*uc
    int s  = (tid >> 10) & 1;
    int c  = tid >> 11;
    int u0 = 8 * uc;
    const float* src = (s ? img_imag : img_real) + c * (DNX * DNY) + y;
    float fp[8], fm[8];
    #pragma unroll
    for (int j = 0; j < 8; ++j) {
        float a = src[(64 + u0 + j) * DNY];
        float b = src[(63 - u0 - j) * DNY];
        fp[j] = a + b;
        fm[j] = a - b;
    }
    int col = 2 * y + s;
    int xo  = 16 * (col & 7);
    int t4p = uc >> 2, q = uc & 3;
    int destp = (256 * col + 64 * t4p       + 16 * q) ^ xo;   // slot u0
    int destm = (256 * col + 64 * (t4p + 2) + 16 * q) ^ xo;   // slot 64+u0
    uint4 vp, vm;
    vp.x = pkbf(fp[0], fp[1]); vp.y = pkbf(fp[2], fp[3]);
    vp.z = pkbf(fp[4], fp[5]); vp.w = pkbf(fp[6], fp[7]);
    vm.x = pkbf(fm[0], fm[1]); vm.y = pkbf(fm[2], fm[3]);
    vm.z = pkbf(fm[4], fm[5]); vm.w = pkbf(fm[6], fm[7]);
    char* base = (char*)B_pre + (size_t)c * 65536;
    *(uint4*)(base + destp) = vp;
    *(uint4*)(base + destm) = vm;
}

// ---------------------------------------------------------------------------
// Main, round-12: CONSOLIDATION — prep_phase fused into the prologue.
// Evidence: r10 proved table-load vs in-kernel trig is time-neutral for main
// (VALU has slack under the MFMA floor), so the phase table bought nothing
// except a dispatch + gap + 128KB of L2 table reads. This round computes the
// folded phases in-kernel (prep2's exact math: angle = pi*d1*(16m+8hi+j+0.5),
// incremental rotation, identical pack order) and deletes prep_phase_kernel.
// ALL other machinery is byte-identical to the PASSING r11: folded prep1,
// DMA staging, LDS bases, 4-chain MFMA, stage-2 combine/rotors, epilogue
// rotation cis(pi*tx/128).
// ---------------------------------------------------------------------------
__global__ __launch_bounds__(512, 1) void nudft_mfma_kernel(
    const float* __restrict__ trj,
    const unsigned short* __restrict__ B_pre,
    float* __restrict__ out)
{
    __shared__ __align__(16) unsigned short Bl[32768];   // 64 KB folded channel

    const int t    = threadIdx.x;     // 0..511
    const int w    = t >> 6;          // wave 0..7
    const int lane = t & 63;
    const int l31  = lane & 31;
    const int hi   = lane >> 5;
    const int kb   = blockIdx.x;      // 0..31
    const int c    = blockIdx.y;      // 0..7
    const int k0w  = kb * 512 + w * 64;
    const int kA   = k0w + l31;        // k-set 0
    const int kB   = k0w + 32 + l31;   // k-set 1

    // ---- trj loads first (4 scalars; results consumed by trig below)
    const float txA = trj[2 * kA];
    const float tyA = trj[2 * kA + 1];
    const float txB = trj[2 * kB];
    const float tyB = trj[2 * kB + 1];

    // ---- stage the whole 64KB folded channel image (DMA overlaps the trig)
    {
        const char* g = (const char*)B_pre + ((size_t)c << 16) + (t << 4);
        char* l = (char*)&Bl[0] + (t << 4);
        #pragma unroll
        for (int i = 0; i < 8; ++i)
            __builtin_amdgcn_global_load_lds(
                (gp_t)(const void*)(g + (i << 13)),
                (lp_t)(void*)(l + (i << 13)), 16, 0, 0);
    }
    __builtin_amdgcn_sched_barrier(0);

    // ---- folded phase fragments, in-kernel (prep2's exact math).
    // Fragment element (m, hi, j): angle = pi * d1 * (16m + 8hi + j + 0.5),
    // d1 = -tx/64. cos -> pc*[m], sin -> ps*[m].
    bf16x8 pc0[4], ps0[4], pc1[4], ps1[4];
    #pragma unroll
    for (int ks = 0; ks < 2; ++ks) {
        const float tx = ks ? txB : txA;
        bf16x8* pcs = ks ? pc1 : pc0;
        bf16x8* pss = ks ? ps1 : ps0;
        const float d1 = -tx * (1.0f / 64.0f);
        float s1, c1;   sincospif(d1, &s1, &c1);            // step per +1
        float s16, c16; sincospif(16.0f * d1, &s16, &c16);  // step per +16 (m)
        float ps, pc;   sincospif(d1 * ((float)(8 * hi) + 0.5f), &ps, &pc);
        #pragma unroll
        for (int m = 0; m < 4; ++m) {
            float qc = pc, qs = ps;
            float fc[8], fs[8];
            #pragma unroll
            for (int j = 0; j < 8; ++j) {
                fc[j] = qc; fs[j] = qs;
                if (j < 7) {
                    float tq = qc * c1 - qs * s1;
                    qs = fmaf(qc, s1, qs * c1);
                    qc = tq;
                }
            }
            uint32_t* pr = (uint32_t*)&pcs[m];
            uint32_t* pi = (uint32_t*)&pss[m];
            #pragma unroll
            for (int p = 0; p < 4; ++p) {
                pr[p] = pkbf(fc[2 * p], fc[2 * p + 1]);
                pi[p] = pkbf(fs[2 * p], fs[2 * p + 1]);
            }
            if (m < 3) {
                float tp = pc * c16 - ps * s16;
                ps = fmaf(pc, s16, ps * c16);
                pc = tp;
            }
        }
    }

    // ---- final per-k rotation cis(pi*tx/128)
    float srA, crA; sincospif(txA * 0.0078125f, &srA, &crA);
    float srB, crB; sincospif(txB * 0.0078125f, &srB, &crB);

    // ---- stage-2 rotors per k-set (verified r10/r11 form)
    float rdiA, rdrA; sincospif(-tyA * 0.25f, &rdiA, &rdrA);
    float rdiB, rdrB; sincospif(-tyB * 0.25f, &rdiB, &rdrB);
    float cbA[8], sbA[8], cbB[8], sbB[8];
    #pragma unroll
    for (int ks = 0; ks < 2; ++ks) {
        const float ty = ks ? tyB : tyA;
        float* cb = ks ? cbB : cbA;
        float* sb = ks ? sbB : sbA;
        float bs, bc; sincospif(-ty * (float)(2 * hi - 64) * (1.0f / 64.0f), &bs, &bc);
        float qs4, qc4; sincospif(-ty * 0.0625f,   &qs4, &qc4);
        float os1, oc1; sincospif(-ty * 0.015625f, &os1, &oc1);
        float rc = bc, rs = bs;
        #pragma unroll
        for (int q = 0; q < 4; ++q) {
            cb[2 * q] = rc;  sb[2 * q] = rs;
            cb[2 * q + 1] = rc * oc1 - rs * os1;
            sb[2 * q + 1] = fmaf(rc, os1, rs * oc1);
            if (q < 3) {
                float tz = rc * qc4 - rs * qs4;
                rs = fmaf(rc, qs4, rs * qc4);
                rc = tz;
            }
        }
    }
    float oreA = 0.f, oimA = 0.f, oreB = 0.f, oimB = 0.f;

    // ---- per-lane LDS bases (identical derivation to r7/r10/r11)
    const int s7 = lane & 7;
    const int u  = s7 >> 1;
    const int v  = hi ^ (s7 & 1);
    const char* baseA = (const char*)&Bl[0] + 256 * l31 + 16 * v;
    const char* B0 = baseA + 32 * (0 ^ u);
    const char* B1 = baseA + 32 * (1 ^ u);
    const char* B2 = baseA + 32 * (2 ^ u);
    const char* B3 = baseA + 32 * (3 ^ u);
    const f32x16 ZER16 = {0.f,0.f,0.f,0.f,0.f,0.f,0.f,0.f,
                          0.f,0.f,0.f,0.f,0.f,0.f,0.f,0.f};

    __syncthreads();   // DMA drained; the ONLY barrier

    #pragma unroll 1
    for (int ct = 0; ct < 8; ++ct) {
        const int off = 8192 * ct;
        bf16x8 f0 = *(const bf16x8*)(B0 + off);          // plus-plane chunks
        bf16x8 f1 = *(const bf16x8*)(B1 + off);
        bf16x8 f2 = *(const bf16x8*)(B2 + off);
        bf16x8 f3 = *(const bf16x8*)(B3 + off);
        bf16x8 f4 = *(const bf16x8*)(B0 + off + 128);    // minus-plane chunks
        bf16x8 f5 = *(const bf16x8*)(B1 + off + 128);
        bf16x8 f6 = *(const bf16x8*)(B2 + off + 128);
        bf16x8 f7 = *(const bf16x8*)(B3 + off + 128);
        f32x16 a1, a2, b1, b2;
        __builtin_amdgcn_s_setprio(1);
        // 4 independent chains (dep distance 4): a = k-set 0, b = k-set 1
        a1 = __builtin_amdgcn_mfma_f32_32x32x16_bf16(f0, pc0[0], ZER16, 0,0,0);
        a2 = __builtin_amdgcn_mfma_f32_32x32x16_bf16(f4, ps0[0], ZER16, 0,0,0);
        b1 = __builtin_amdgcn_mfma_f32_32x32x16_bf16(f0, pc1[0], ZER16, 0,0,0);
        b2 = __builtin_amdgcn_mfma_f32_32x32x16_bf16(f4, ps1[0], ZER16, 0,0,0);
        a1 = __builtin_amdgcn_mfma_f32_32x32x16_bf16(f1, pc0[1], a1,    0,0,0);
        a2 = __builtin_amdgcn_mfma_f32_32x32x16_bf16(f5, ps0[1], a2,    0,0,0);
        b1 = __builtin_amdgcn_mfma_f32_32x32x16_bf16(f1, pc1[1], b1,    0,0,0);
        b2 = __builtin_amdgcn_mfma_f32_32x32x16_bf16(f5, ps1[1], b2,    0,0,0);
        a1 = __builtin_amdgcn_mfma_f32_32x32x16_bf16(f2, pc0[2], a1,    0,0,0);
        a2 = __builtin_amdgcn_mfma_f32_32x32x16_bf16(f6, ps0[2], a2,    0,0,0);
        b1 = __builtin_amdgcn_mfma_f32_32x32x16_bf16(f2, pc1[2], b1,    0,0,0);
        b2 = __builtin_amdgcn_mfma_f32_32x32x16_bf16(f6, ps1[2], b2,    0,0,0);
        a1 = __builtin_amdgcn_mfma_f32_32x32x16_bf16(f3, pc0[3], a1,    0,0,0);
        a2 = __builtin_amdgcn_mfma_f32_32x32x16_bf16(f7, ps0[3], a2,    0,0,0);
        b1 = __builtin_amdgcn_mfma_f32_32x32x16_bf16(f3, pc1[3], b1,    0,0,0);
        b2 = __builtin_amdgcn_mfma_f32_32x32x16_bf16(f7, ps1[3], b2,    0,0,0);
        __builtin_amdgcn_s_setprio(0);
        // stage 2 per k-set (combine signs verified r7/r10/r11)
        #pragma unroll
        for (int q = 0; q < 4; ++q) {
            #pragma unroll
            for (int j = 0; j < 2; ++j) {
                const int e = 4 * q + 2 * j;
                const int p = 2 * q + j;
                {
                    float Sre = a1[e]     - a2[e + 1];
                    float Sim = a1[e + 1] + a2[e];
                    oreA = fmaf(Sre,  cbA[p], oreA);
                    oreA = fmaf(-Sim, sbA[p], oreA);
                    oimA = fmaf(Sre,  sbA[p], oimA);
                    oimA = fmaf(Sim,  cbA[p], oimA);
                }
                {
                    float Sre = b1[e]     - b2[e + 1];
                    float Sim = b1[e + 1] + b2[e];
                    oreB = fmaf(Sre,  cbB[p], oreB);
                    oreB = fmaf(-Sim, sbB[p], oreB);
                    oimB = fmaf(Sre,  sbB[p], oimB);
                    oimB = fmaf(Sim,  cbB[p], oimB);
                }
            }
        }
        // advance rotors (y += 16)
        #pragma unroll
        for (int p = 0; p < 8; ++p) {
            float tzA = cbA[p] * rdrA - sbA[p] * rdiA;
            sbA[p] = fmaf(cbA[p], rdiA, sbA[p] * rdrA);
            cbA[p] = tzA;
            float tzB = cbB[p] * rdrB - sbB[p] * rdiB;
            sbB[p] = fmaf(cbB[p], rdiB, sbB[p] * rdrB);
            cbB[p] = tzB;
        }
    }

    // ---- epilogue: fold lane-halves, apply final rotation cis(pi*tx/128)
    {
        float r0 = oreA + __shfl_xor(oreA, 32);
        float i0 = oimA + __shfl_xor(oimA, 32);
        float r1 = oreB + __shfl_xor(oreB, 32);
        float i1 = oimB + __shfl_xor(oimB, 32);
        if (lane < 32) {
            out[(size_t)c * KPTS + kA]                      = r0 * crA - i0 * srA;
            out[(size_t)NCH * KPTS + (size_t)c * KPTS + kA] = fmaf(r0, srA, i0 * crA);
            out[(size_t)c * KPTS + kB]                      = r1 * crB - i1 * srB;
            out[(size_t)NCH * KPTS + (size_t)c * KPTS + kB] = fmaf(r1, srB, i1 * crB);
        }
    }
}

extern "C" void kernel_launch(void* const* d_in, const int* in_sizes, int n_in,
                              void* d_out, int out_size, void* d_ws, size_t ws_size,
                              hipStream_t stream)
{
    const float* img_real = (const float*)d_in[0];  // (8,128,128) fp32
    const float* img_imag = (const float*)d_in[1];  // (8,128,128) fp32
    const float* trj      = (const float*)d_in[2];  // (16384,2) fp32
    float* out = (float*)d_out;                      // planar: re block then im block
    unsigned short* B_pre = (unsigned short*)d_ws;   // 512 KB (folded)

    prep_kernel<<<64, 256, 0, stream>>>(img_real, img_imag, B_pre);
    nudft_mfma_kernel<<<dim3(32, 8), 512, 0, stream>>>(trj, B_pre, out);
}

// Round 13
// 73.062 us; speedup vs baseline: 1.8044x; 1.0052x over previous
//
#include <hip/hip_runtime.h>
#include <hip/hip_bf16.h>
#include <math.h>
#include <stdint.h>

// Problem constants
#define NCH   8
#define DNX   128
#define DNY   128
#define KPTS  16384

typedef __attribute__((ext_vector_type(8)))  short bf16x8;   // MFMA A/B frag (8 bf16)
typedef __attribute__((ext_vector_type(16))) float f32x16;   // 32x32 MFMA C/D frag

typedef const __attribute__((address_space(1))) unsigned int* gp_t;
typedef __attribute__((address_space(3))) unsigned int* lp_t;

// pack two fp32 -> one uint32 of two bf16 (RNE)
__device__ __forceinline__ uint32_t pkbf(float lo, float hi) {
    union { __hip_bfloat162 h; uint32_t u; } v;
    v.h = __float22bfloat162_rn(make_float2(lo, hi));
    return v.u;
}

// ---------------------------------------------------------------------------
// Prep (UNCHANGED from verified r11/r12): img -> B_pre with center-symmetric
// x-fold. u' = 0..63: f_plus(u',y) = f(64+u',y)+f(63-u',y) -> x-slot u';
// f_minus -> x-slot 64+u'. dest(x_slot,col) =
// (256*col + 64*t4 + 16*q) ^ (16*(col&7)), col = 2y+s.
// ---------------------------------------------------------------------------
__global__ __launch_bounds__(256) void prep_kernel(
    const float* __restrict__ img_real,
    const float* __restrict__ img_imag,
    unsigned short* __restrict__ B_pre)
{
    int tid = blockIdx.x * 256 + threadIdx.x;   // 16384 threads total
    int y  = tid & 127;
    int uc = (tid >> 7) & 7;                    // u-chunk 0..7, u0 = 8*uc
    int s  = (tid >> 10) & 1;
    int c  = tid >> 11;
    int u0 = 8 * uc;
    const float* src = (s ? img_imag : img_real) + c * (DNX * DNY) + y;
    float fp[8], fm[8];
    #pragma unroll
    for (int j = 0; j < 8; ++j) {
        float a = src[(64 + u0 + j) * DNY];
        float b = src[(63 - u0 - j) * DNY];
        fp[j] = a + b;
        fm[j] = a - b;
    }
    int col = 2 * y + s;
    int xo  = 16 * (col & 7);
    int t4p = uc >> 2, q = uc & 3;
    int destp = (256 * col + 64 * t4p       + 16 * q) ^ xo;   // slot u0
    int destm = (256 * col + 64 * (t4p + 2) + 16 * q) ^ xo;   // slot 64+u0
    uint4 vp, vm;
    vp.x = pkbf(fp[0], fp[1]); vp.y = pkbf(fp[2], fp[3]);
    vp.z = pkbf(fp[4], fp[5]); vp.w = pkbf(fp[6], fp[7]);
    vm.x = pkbf(fm[0], fm[1]); vm.y = pkbf(fm[2], fm[3]);
    vm.z = pkbf(fm[4], fm[5]); vm.w = pkbf(fm[6], fm[7]);
    char* base = (char*)B_pre + (size_t)c * 65536;
    *(uint4*)(base + destp) = vp;
    *(uint4*)(base + destm) = vm;
}

// ---------------------------------------------------------------------------
// Main, round-13: OCCUPANCY FOR OVERLAP — one k-set per wave.
// Cycle-model fit of r6-r12: at 2 waves/SIMD the pipes partially SERIALIZE
// (r12 main ~28us ~= MFMA 8192 + VALU 6400 + partial LDS cyc at low clock);
// at 4 waves/SIMD time ~= max(pipes) (r6 evidence). r12's ~210 VGPR forced
// 2 waves/SIMD. This round: each wave owns 32 k (ONE k-set) -> phases 32,
// accs 32, rotors 16 regs -> ~118 VGPR < 128 cap. Grid (64,8) = 512 blocks
// = exactly 2 blocks/CU (LDS 128<=160KB), (512,2) -> 4 waves/SIMD.
// All instruction paths are verbatim from the PASSING r12 (k-set B deleted).
// ---------------------------------------------------------------------------
__global__ __launch_bounds__(512, 2) void nudft_mfma_kernel(
    const float* __restrict__ trj,
    const unsigned short* __restrict__ B_pre,
    float* __restrict__ out)
{
    __shared__ __align__(16) unsigned short Bl[32768];   // 64 KB folded channel

    const int t    = threadIdx.x;     // 0..511
    const int w    = t >> 6;          // wave 0..7
    const int lane = t & 63;
    const int l31  = lane & 31;
    const int hi   = lane >> 5;
    const int kb   = blockIdx.x;      // 0..63
    const int c    = blockIdx.y;      // 0..7
    const int k    = kb * 256 + w * 32 + l31;   // this lane's k-point

    // ---- trj loads first
    const float tx = trj[2 * k];
    const float ty = trj[2 * k + 1];

    // ---- stage the whole 64KB folded channel image (DMA overlaps the trig)
    {
        const char* g = (const char*)B_pre + ((size_t)c << 16) + (t << 4);
        char* l = (char*)&Bl[0] + (t << 4);
        #pragma unroll
        for (int i = 0; i < 8; ++i)
            __builtin_amdgcn_global_load_lds(
                (gp_t)(const void*)(g + (i << 13)),
                (lp_t)(void*)(l + (i << 13)), 16, 0, 0);
    }
    __builtin_amdgcn_sched_barrier(0);

    // ---- folded phase fragments, in-kernel (r12's verified math).
    // Fragment element (m, hi, j): angle = pi * d1 * (16m + 8hi + j + 0.5),
    // d1 = -tx/64. cos -> pc[m], sin -> ps[m].
    bf16x8 pc[4], psn[4];
    {
        const float d1 = -tx * (1.0f / 64.0f);
        float s1, c1;   sincospif(d1, &s1, &c1);            // step per +1
        float s16, c16; sincospif(16.0f * d1, &s16, &c16);  // step per +16 (m)
        float ps, pcv;  sincospif(d1 * ((float)(8 * hi) + 0.5f), &ps, &pcv);
        #pragma unroll
        for (int m = 0; m < 4; ++m) {
            float qc = pcv, qs = ps;
            float fc[8], fs[8];
            #pragma unroll
            for (int j = 0; j < 8; ++j) {
                fc[j] = qc; fs[j] = qs;
                if (j < 7) {
                    float tq = qc * c1 - qs * s1;
                    qs = fmaf(qc, s1, qs * c1);
                    qc = tq;
                }
            }
            uint32_t* pr = (uint32_t*)&pc[m];
            uint32_t* pi = (uint32_t*)&psn[m];
            #pragma unroll
            for (int p = 0; p < 4; ++p) {
                pr[p] = pkbf(fc[2 * p], fc[2 * p + 1]);
                pi[p] = pkbf(fs[2 * p], fs[2 * p + 1]);
            }
            if (m < 3) {
                float tp = pcv * c16 - ps * s16;
                ps  = fmaf(pcv, s16, ps * c16);
                pcv = tp;
            }
        }
    }

    // ---- final per-k rotation cis(pi*tx/128)
    float srR, crR; sincospif(tx * 0.0078125f, &srR, &crR);

    // ---- stage-2 rotors (r12's verified form)
    float rdi, rdr; sincospif(-ty * 0.25f, &rdi, &rdr);
    float cb[8], sb[8];
    {
        float bs, bc; sincospif(-ty * (float)(2 * hi - 64) * (1.0f / 64.0f), &bs, &bc);
        float qs4, qc4; sincospif(-ty * 0.0625f,   &qs4, &qc4);
        float os1, oc1; sincospif(-ty * 0.015625f, &os1, &oc1);
        float rc = bc, rs = bs;
        #pragma unroll
        for (int q = 0; q < 4; ++q) {
            cb[2 * q] = rc;  sb[2 * q] = rs;
            cb[2 * q + 1] = rc * oc1 - rs * os1;
            sb[2 * q + 1] = fmaf(rc, os1, rs * oc1);
            if (q < 3) {
                float tz = rc * qc4 - rs * qs4;
                rs = fmaf(rc, qs4, rs * qc4);
                rc = tz;
            }
        }
    }
    float ore = 0.f, oim = 0.f;

    // ---- per-lane LDS bases (identical derivation to r7/r10/r11/r12)
    const int s7 = lane & 7;
    const int u  = s7 >> 1;
    const int v  = hi ^ (s7 & 1);
    const char* baseA = (const char*)&Bl[0] + 256 * l31 + 16 * v;
    const char* B0 = baseA + 32 * (0 ^ u);
    const char* B1 = baseA + 32 * (1 ^ u);
    const char* B2 = baseA + 32 * (2 ^ u);
    const char* B3 = baseA + 32 * (3 ^ u);
    const f32x16 ZER16 = {0.f,0.f,0.f,0.f,0.f,0.f,0.f,0.f,
                          0.f,0.f,0.f,0.f,0.f,0.f,0.f,0.f};

    __syncthreads();   // DMA drained; the ONLY barrier

    #pragma unroll 1
    for (int ct = 0; ct < 8; ++ct) {
        const int off = 8192 * ct;
        bf16x8 f0 = *(const bf16x8*)(B0 + off);          // plus-plane chunks
        bf16x8 f1 = *(const bf16x8*)(B1 + off);
        bf16x8 f2 = *(const bf16x8*)(B2 + off);
        bf16x8 f3 = *(const bf16x8*)(B3 + off);
        bf16x8 f4 = *(const bf16x8*)(B0 + off + 128);    // minus-plane chunks
        bf16x8 f5 = *(const bf16x8*)(B1 + off + 128);
        bf16x8 f6 = *(const bf16x8*)(B2 + off + 128);
        bf16x8 f7 = *(const bf16x8*)(B3 + off + 128);
        f32x16 a1, a2;
        __builtin_amdgcn_s_setprio(1);
        // 2 chains, dep distance 2 (4-wave TLP covers the latency)
        a1 = __builtin_amdgcn_mfma_f32_32x32x16_bf16(f0, pc[0],  ZER16, 0,0,0);
        a2 = __builtin_amdgcn_mfma_f32_32x32x16_bf16(f4, psn[0], ZER16, 0,0,0);
        a1 = __builtin_amdgcn_mfma_f32_32x32x16_bf16(f1, pc[1],  a1,    0,0,0);
        a2 = __builtin_amdgcn_mfma_f32_32x32x16_bf16(f5, psn[1], a2,    0,0,0);
        a1 = __builtin_amdgcn_mfma_f32_32x32x16_bf16(f2, pc[2],  a1,    0,0,0);
        a2 = __builtin_amdgcn_mfma_f32_32x32x16_bf16(f6, psn[2], a2,    0,0,0);
        a1 = __builtin_amdgcn_mfma_f32_32x32x16_bf16(f3, pc[3],  a1,    0,0,0);
        a2 = __builtin_amdgcn_mfma_f32_32x32x16_bf16(f7, psn[3], a2,    0,0,0);
        __builtin_amdgcn_s_setprio(0);
        // stage 2 (combine signs verified r7/r10/r11/r12)
        #pragma unroll
        for (int q = 0; q < 4; ++q) {
            #pragma unroll
            for (int j = 0; j < 2; ++j) {
                const int e = 4 * q + 2 * j;
                const int p = 2 * q + j;
                float Sre = a1[e]     - a2[e + 1];
                float Sim = a1[e + 1] + a2[e];
                ore = fmaf(Sre,  cb[p], ore);
                ore = fmaf(-Sim, sb[p], ore);
                oim = fmaf(Sre,  sb[p], oim);
                oim = fmaf(Sim,  cb[p], oim);
            }
        }
        // advance rotors (y += 16)
        #pragma unroll
        for (int p = 0; p < 8; ++p) {
            float tz = cb[p] * rdr - sb[p] * rdi;
            sb[p] = fmaf(cb[p], rdi, sb[p] * rdr);
            cb[p] = tz;
        }
    }

    // ---- epilogue: fold lane-halves, apply final rotation cis(pi*tx/128)
    {
        float r0 = ore + __shfl_xor(ore, 32);
        float i0 = oim + __shfl_xor(oim, 32);
        if (lane < 32) {
            out[(size_t)c * KPTS + k]                      = r0 * crR - i0 * srR;
            out[(size_t)NCH * KPTS + (size_t)c * KPTS + k] = fmaf(r0, srR, i0 * crR);
        }
    }
}

extern "C" void kernel_launch(void* const* d_in, const int* in_sizes, int n_in,
                              void* d_out, int out_size, void* d_ws, size_t ws_size,
                              hipStream_t stream)
{
    const float* img_real = (const float*)d_in[0];  // (8,128,128) fp32
    const float* img_imag = (const float*)d_in[1];  // (8,128,128) fp32
    const float* trj      = (const float*)d_in[2];  // (16384,2) fp32
    float* out = (float*)d_out;                      // planar: re block then im block
    unsigned short* B_pre = (unsigned short*)d_ws;   // 512 KB (folded)

    prep_kernel<<<64, 256, 0, stream>>>(img_real, img_imag, B_pre);
    nudft_mfma_kernel<<<dim3(64, 8), 512, 0, stream>>>(trj, B_pre, out);
}